// Round 1
// baseline (12783.054 us; speedup 1.0000x reference)
//
#include <hip/hip_runtime.h>
#include <hip/hip_bf16.h>
#include <stdint.h>

// Problem constants
#define N_B     64
#define T_STEPS 1024
#define T1      1025
#define VOCAB   10000
#define DIM     512
#define HID     512
#define FOURH   2048
#define GBLK    32      // workgroups in persistent scan kernel (16 hid dims each)
#define FLGSTR  32      // u32 stride between block flags (128 B, own L2 line)

typedef unsigned short u16;
typedef unsigned int   u32;
typedef short bf16x8 __attribute__((ext_vector_type(8)));   // 8 bf16 = 4 VGPRs
typedef float f32x16 __attribute__((ext_vector_type(16)));  // 32x32 MFMA acc

__device__ __forceinline__ float bf2f(u16 x){
  union { u32 u; float f; } v; v.u = ((u32)x) << 16; return v.f;
}
__device__ __forceinline__ u16 f2bf(float f){
  union { float f; u32 u; } v; v.f = f;
  u32 u = v.u;
  return (u16)((u + 0x7FFFu + ((u >> 16) & 1u)) >> 16);  // RNE
}
__device__ __forceinline__ bf16x8 ldfrag(const u16* p){
  union { uint4 q; bf16x8 s; } v; v.q = *(const uint4*)p; return v.s;
}
__device__ __forceinline__ float fsig(float x){
  return 1.0f / (1.0f + exp2f(x * -1.44269504f));
}
__device__ __forceinline__ float ftanh(float x){
  return 1.0f - 2.0f / (1.0f + exp2f(x * 2.88539008f));  // saturates at +/-1
}

// ---- transpose+convert Wx, Wh (512 x 2048 fp32) -> bf16 (2048 x 512) ----
__global__ void k_transpose(const float* __restrict__ Wx, const float* __restrict__ Wh,
                            u16* __restrict__ WxT, u16* __restrict__ WhT){
  int b = blockIdx.x;
  const float* src = Wx; u16* dst = WxT;
  if (b >= 512){ src = Wh; dst = WhT; b -= 512; }
  int id = b * 256 + threadIdx.x;       // 131072 ids: 2048 cols x 64 k-chunks
  int n  = id & (FOURH - 1);            // source col (consecutive per lane -> coalesced)
  int kc = (id >> 11) << 3;             // k chunk of 8
  u32 w[4];
  #pragma unroll
  for (int j = 0; j < 4; j++){
    u32 lo = (u32)f2bf(src[(kc + 2*j    ) * FOURH + n]);
    u32 hi = (u32)f2bf(src[(kc + 2*j + 1) * FOURH + n]);
    w[j] = lo | (hi << 16);
  }
  uint4 q; q.x = w[0]; q.y = w[1]; q.z = w[2]; q.w = w[3];
  *(uint4*)(dst + n * DIM + kc) = q;
}

// ---- convert W_embed (10000 x 512 fp32) -> bf16, same layout ----
__global__ void k_wemb(const float* __restrict__ Wemb, u16* __restrict__ We16){
  int i = blockIdx.x * 256 + threadIdx.x;        // 2,560,000 ids, 2 elems each
  float2 f = *(const float2*)(Wemb + 2 * i);
  u32 pk = (u32)f2bf(f.x) | ((u32)f2bf(f.y) << 16);
  *(u32*)(We16 + 2 * i) = pk;
}

// ---- init h buffers (hi/lo split of fp32 h0) + barrier flags ----
__global__ void k_init(const float* __restrict__ h0, u16* __restrict__ h_hi,
                       u16* __restrict__ h_lo, u32* flags){
  int i = blockIdx.x * 256 + threadIdx.x;   // 32768
  float f = h0[i];
  u16 hb = f2bf(f);
  h_hi[i] = hb;
  h_lo[i] = f2bf(f - bf2f(hb));
  if (i < GBLK * FLGSTR) flags[i] = 0;
}

// ---- E = W_embed @ Wx + b  (10000 x 2048, bf16) ----
__launch_bounds__(256)
__global__ void k_egemm(const u16* __restrict__ Wemb, const u16* __restrict__ WxT,
                        const float* __restrict__ bias, u16* __restrict__ E){
  int nb = blockIdx.x;            // 0..15  -> cols nb*128
  int mb = blockIdx.y;            // 0..78  -> rows mb*128
  int wv   = threadIdx.x >> 6;
  int lane = threadIdx.x & 63;
  int l31 = lane & 31, hi5 = lane >> 5;
  int mrow = mb * 128 + wv * 32 + l31;
  int mcl  = mrow < VOCAB ? mrow : VOCAB - 1;
  const u16* ap  = Wemb + (u32)mcl * DIM + hi5 * 8;
  const u16* bp0 = WxT + (u32)(nb * 128 +  0 + l31) * DIM + hi5 * 8;
  const u16* bp1 = bp0 + 32 * DIM;
  const u16* bp2 = bp0 + 64 * DIM;
  const u16* bp3 = bp0 + 96 * DIM;
  f32x16 acc[4] = {};
  for (int ks = 0; ks < 32; ks++){
    bf16x8 av = ldfrag(ap);  ap  += 16;
    bf16x8 b0 = ldfrag(bp0); bp0 += 16;
    bf16x8 b1 = ldfrag(bp1); bp1 += 16;
    bf16x8 b2 = ldfrag(bp2); bp2 += 16;
    bf16x8 b3 = ldfrag(bp3); bp3 += 16;
    acc[0] = __builtin_amdgcn_mfma_f32_32x32x16_bf16(av, b0, acc[0], 0, 0, 0);
    acc[1] = __builtin_amdgcn_mfma_f32_32x32x16_bf16(av, b1, acc[1], 0, 0, 0);
    acc[2] = __builtin_amdgcn_mfma_f32_32x32x16_bf16(av, b2, acc[2], 0, 0, 0);
    acc[3] = __builtin_amdgcn_mfma_f32_32x32x16_bf16(av, b3, acc[3], 0, 0, 0);
  }
  int rbase = mb * 128 + wv * 32 + 4 * hi5;
  #pragma unroll
  for (int nt = 0; nt < 4; nt++){
    int col = nb * 128 + nt * 32 + l31;
    float bv = bias[col];
    #pragma unroll
    for (int r = 0; r < 16; r++){
      int row = rbase + (r & 3) + 8 * (r >> 2);
      if (row < VOCAB) E[(u32)row * FOURH + col] = f2bf(acc[nt][r] + bv);
    }
  }
}

// ---- persistent LSTM scan ----
// 32 blocks x 256 threads (4 waves). Block b owns hidden dims [b*16, b*16+16).
// Wave wv: col-tile ct = wv>>1 (8-dim slice cs = b*2+ct), batch half bh = wv&1.
// GEMM computed transposed: D = WhSlice^T(32 x K) . h^T(K x 32n) so that
// gate = reg&3 lands in the register dim -> all 4 gates in-lane.
//
// Fence-free publish: h stored via RELAXED AGENT atomics (write-through to the
// coherence point -> no dirty L2 -> no buffer_wbl2 release needed). The
// __syncthreads() before the flag store drains vmcnt in every wave, so all h
// stores are globally visible when the (relaxed) flag store is issued. Readers
// poll relaxed-agent flags, then one acquire fence (L1+L2 invalidate) so the
// bulk h loads can stay as plain cached dwordx4.
__launch_bounds__(256, 1)
__global__ void k_scan(const int* __restrict__ cap, const u16* __restrict__ E,
                       const u16* __restrict__ WhT, u16* __restrict__ h_hi,
                       u16* __restrict__ h_lo, u32* flags, float* __restrict__ out){
  const int b    = blockIdx.x;              // 0..31
  const int tid  = threadIdx.x;             // 0..255
  const int wv   = tid >> 6;                // 0..3
  const int lane = tid & 63;
  const int l31  = lane & 31, hi5 = lane >> 5;
  const int cs   = b * 2 + (wv >> 1);       // 0..63 : 8-dim gate-column slice
  const int n    = (wv & 1) * 32 + l31;     // batch row (B-operand col)
  // A-operand row r_loc = l31 -> global Wh column:
  const int gc   = (l31 & 3) * HID + cs * 8 + (l31 >> 2);
  const u16* wbase = WhT + (u32)gc * DIM + hi5 * 8;

  // Wh slice is static across all 1024 steps: hold it in registers (128 VGPRs).
  bf16x8 wreg[32];
  #pragma unroll
  for (int ks = 0; ks < 32; ks++) wreg[ks] = ldfrag(wbase + 16 * ks);

  float c0 = 0.f, c1 = 0.f, c2 = 0.f, c3 = 0.f;

  // prefetch E row for t=0
  int capv = cap[n * T1];
  const u16* eb = E + (u32)capv * FOURH + cs * 8;
  uint4 e0 = *(const uint4*)(eb + 0 * HID);
  uint4 e1 = *(const uint4*)(eb + 1 * HID);
  uint4 e2 = *(const uint4*)(eb + 2 * HID);
  uint4 e3 = *(const uint4*)(eb + 3 * HID);

  for (int t = 0; t < T_STEPS; t++){
    // acc init from prefetched E (xW + b contribution) — independent of other
    // blocks' h, so done BEFORE the wait to shorten the post-barrier path.
    u32 ew[16];
    *(uint4*)&ew[0]  = e0; *(uint4*)&ew[4]  = e1;
    *(uint4*)&ew[8]  = e2; *(uint4*)&ew[12] = e3;
    f32x16 acc;
    #pragma unroll
    for (int reg = 0; reg < 16; reg++){
      int gate = reg & 3, q = reg >> 2;
      u32 d = ew[gate * 4 + q];
      acc[reg] = bf2f(hi5 ? (u16)(d >> 16) : (u16)(d & 0xFFFFu));
    }
    f32x16 acc2 = {};

    if (t > 0){
      if (tid < 64){
        u32 v;
        do {
          v = (lane < GBLK)
                ? __hip_atomic_load(&flags[lane * FLGSTR], __ATOMIC_RELAXED,
                                    __HIP_MEMORY_SCOPE_AGENT)
                : 0xFFFFFFFFu;
        } while (__ballot(v < (u32)t));
        // one L1/L2 invalidate per step (covers this CU's waves + this XCD)
        __builtin_amdgcn_fence(__ATOMIC_ACQUIRE, "agent");
      }
      __syncthreads();
    }

    // K-loop: a += Wh^T-slice . h  (h = hi + lo bf16 pair, fp32 accumulate)
    const u16* hp = h_hi + (t & 1) * (N_B * HID) + n * HID + hi5 * 8;
    const u16* lp = h_lo + (t & 1) * (N_B * HID) + n * HID + hi5 * 8;
    #pragma unroll
    for (int ks = 0; ks < 32; ks++){
      bf16x8 bhf = ldfrag(hp); hp += 16;
      bf16x8 blf = ldfrag(lp); lp += 16;
      acc  = __builtin_amdgcn_mfma_f32_32x32x16_bf16(wreg[ks], bhf, acc,  0, 0, 0);
      acc2 = __builtin_amdgcn_mfma_f32_32x32x16_bf16(wreg[ks], blf, acc2, 0, 0, 0);
    }
    acc += acc2;

    // LSTM cell: lane holds gates for (n, hd = cs*8 + 2q + hi5), q = 0..3
    u16* hw = h_hi + ((t + 1) & 1) * (N_B * HID);
    u16* lw = h_lo + ((t + 1) & 1) * (N_B * HID);
    const int hbase = n * HID + cs * 8;
    float hq0, hq1, hq2, hq3;
    #pragma unroll
    for (int q = 0; q < 4; q++){
      float ai = acc[q * 4 + 0], af = acc[q * 4 + 1];
      float ao = acc[q * 4 + 2], ag = acc[q * 4 + 3];
      float ig = fsig(ai), fg = fsig(af), og = fsig(ao), gg = ftanh(ag);
      float cc = (q == 0 ? c0 : q == 1 ? c1 : q == 2 ? c2 : c3);
      cc = fg * cc + ig * gg;
      if (q == 0) c0 = cc; else if (q == 1) c1 = cc; else if (q == 2) c2 = cc; else c3 = cc;
      float h = og * ftanh(cc);
      if (q == 0) hq0 = h; else if (q == 1) hq1 = h; else if (q == 2) hq2 = h; else hq3 = h;
      // bf16 hi/lo carry for the recurrence — write-through agent atomics so
      // vmcnt(0) drain == globally visible (no release fence / wbl2 needed).
      u32 hb = f2bf(h);
      float rem = h - bf2f((u16)hb);
      u32 lb = f2bf(rem);
      u32 ph = (u32)__shfl_xor((int)hb, 32);
      u32 pl = (u32)__shfl_xor((int)lb, 32);
      if (hi5 == 0){
        __hip_atomic_store((u32*)(hw + hbase + 2 * q), hb | (ph << 16),
                           __ATOMIC_RELAXED, __HIP_MEMORY_SCOPE_AGENT);
        __hip_atomic_store((u32*)(lw + hbase + 2 * q), lb | (pl << 16),
                           __ATOMIC_RELAXED, __HIP_MEMORY_SCOPE_AGENT);
      }
    }
    __syncthreads();            // every wave drains vmcnt before s_barrier =>
                                // all h stores are at the coherence point
    if (tid == 0)
      __hip_atomic_store(&flags[b * FLGSTR], (u32)(t + 1),
                         __ATOMIC_RELAXED, __HIP_MEMORY_SCOPE_AGENT);

    // off the critical path (after publish): fp32 out stores + next E prefetch.
    // Block owns 16 dims -> the two cs slices cover one full 64B line per (n,t).
    const int obase = n * (T_STEPS * HID) + t * HID + cs * 8;
    __builtin_nontemporal_store(hq0, &out[obase + 0 + hi5]);
    __builtin_nontemporal_store(hq1, &out[obase + 2 + hi5]);
    __builtin_nontemporal_store(hq2, &out[obase + 4 + hi5]);
    __builtin_nontemporal_store(hq3, &out[obase + 6 + hi5]);
    capv = cap[n * T1 + t + 1];   // t+1 <= 1024 < T1, always in-bounds
    const u16* eb2 = E + (u32)capv * FOURH + cs * 8;
    e0 = *(const uint4*)(eb2 + 0 * HID);
    e1 = *(const uint4*)(eb2 + 1 * HID);
    e2 = *(const uint4*)(eb2 + 2 * HID);
    e3 = *(const uint4*)(eb2 + 3 * HID);
  }
}

extern "C" void kernel_launch(void* const* d_in, const int* in_sizes, int n_in,
                              void* d_out, int out_size, void* d_ws, size_t ws_size,
                              hipStream_t stream){
  const int*   cap  = (const int*)d_in[0];
  const float* h0   = (const float*)d_in[1];
  const float* Wemb = (const float*)d_in[2];
  const float* Wx   = (const float*)d_in[3];
  const float* Wh   = (const float*)d_in[4];
  const float* bias = (const float*)d_in[5];
  float* out = (float*)d_out;

  char* ws = (char*)d_ws;
  const size_t OFF_E    = 0;
  const size_t OFF_WXT  = OFF_E    + (size_t)VOCAB * FOURH * 2;   // 40,960,000
  const size_t OFF_WHT  = OFF_WXT  + (size_t)FOURH * DIM * 2;     // +2 MiB
  const size_t OFF_WE16 = OFF_WHT  + (size_t)FOURH * DIM * 2;     // +2 MiB
  const size_t OFF_HHI  = OFF_WE16 + (size_t)VOCAB * DIM * 2;     // +10.24 MB
  const size_t OFF_HLO  = OFF_HHI  + (size_t)2 * N_B * HID * 2;   // +128 KiB
  const size_t OFF_FLG  = OFF_HLO  + (size_t)2 * N_B * HID * 2;   // +128 KiB

  u16* E    = (u16*)(ws + OFF_E);
  u16* WxT  = (u16*)(ws + OFF_WXT);
  u16* WhT  = (u16*)(ws + OFF_WHT);
  u16* We16 = (u16*)(ws + OFF_WE16);
  u16* h_hi = (u16*)(ws + OFF_HHI);
  u16* h_lo = (u16*)(ws + OFF_HLO);
  u32* flg  = (u32*)(ws + OFF_FLG);

  hipLaunchKernelGGL(k_transpose, dim3(1024),   dim3(256), 0, stream, Wx, Wh, WxT, WhT);
  hipLaunchKernelGGL(k_wemb,      dim3(10000),  dim3(256), 0, stream, Wemb, We16);
  hipLaunchKernelGGL(k_init,      dim3(128),    dim3(256), 0, stream, h0, h_hi, h_lo, flg);
  hipLaunchKernelGGL(k_egemm,     dim3(16, 79), dim3(256), 0, stream, We16, WxT, bias, E);
  hipLaunchKernelGGL(k_scan,      dim3(GBLK),   dim3(256), 0, stream, cap, E, WhT, h_hi, h_lo, flg, out);
}

// Round 2
// 11035.508 us; speedup vs baseline: 1.1584x; 1.1584x over previous
//
#include <hip/hip_runtime.h>
#include <hip/hip_bf16.h>
#include <stdint.h>

// Problem constants
#define N_B     64
#define T_STEPS 1024
#define T1      1025
#define VOCAB   10000
#define DIM     512
#define HID     512
#define FOURH   2048
#define GBLK    64      // workgroups in persistent scan kernel (8 hid dims each)
#define FLGSTR  32      // u32 stride between block flags (128 B, own L2 line)

typedef unsigned short u16;
typedef unsigned int   u32;
typedef unsigned long long u64;
typedef short bf16x8 __attribute__((ext_vector_type(8)));   // 8 bf16 = 4 VGPRs
typedef float f32x16 __attribute__((ext_vector_type(16)));  // 32x32 MFMA acc

__device__ __forceinline__ float bf2f(u16 x){
  union { u32 u; float f; } v; v.u = ((u32)x) << 16; return v.f;
}
__device__ __forceinline__ u16 f2bf(float f){
  union { float f; u32 u; } v; v.f = f;
  u32 u = v.u;
  return (u16)((u + 0x7FFFu + ((u >> 16) & 1u)) >> 16);  // RNE
}
__device__ __forceinline__ bf16x8 ldfrag(const u16* p){
  union { uint4 q; bf16x8 s; } v; v.q = *(const uint4*)p; return v.s;
}
// Coherent 16B fragment load: two 8B relaxed agent-scope atomic loads.
// Reads the coherence point (MALL) directly -> sees other XCDs' write-through
// h stores WITHOUT any L1/L2 invalidate. Pipelines like normal loads (vmcnt).
__device__ __forceinline__ bf16x8 ldfrag_coh(const u16* p){
  union { u64 d[2]; bf16x8 s; } v;
  v.d[0] = __hip_atomic_load((const u64*)p,       __ATOMIC_RELAXED, __HIP_MEMORY_SCOPE_AGENT);
  v.d[1] = __hip_atomic_load((const u64*)(p + 4), __ATOMIC_RELAXED, __HIP_MEMORY_SCOPE_AGENT);
  return v.s;
}
// Coherent 16B store: two 8B relaxed agent-scope atomic stores (write-through).
__device__ __forceinline__ void st_coh16(u16* p, u32 w0, u32 w1, u32 w2, u32 w3){
  __hip_atomic_store((u64*)p,       (u64)w0 | ((u64)w1 << 32), __ATOMIC_RELAXED, __HIP_MEMORY_SCOPE_AGENT);
  __hip_atomic_store((u64*)(p + 4), (u64)w2 | ((u64)w3 << 32), __ATOMIC_RELAXED, __HIP_MEMORY_SCOPE_AGENT);
}
__device__ __forceinline__ float fsig(float x){
  return 1.0f / (1.0f + exp2f(x * -1.44269504f));
}
__device__ __forceinline__ float ftanh(float x){
  return 1.0f - 2.0f / (1.0f + exp2f(x * 2.88539008f));  // saturates at +/-1
}

// ---- transpose+convert Wx, Wh (512 x 2048 fp32) -> bf16 (2048 x 512) ----
__global__ void k_transpose(const float* __restrict__ Wx, const float* __restrict__ Wh,
                            u16* __restrict__ WxT, u16* __restrict__ WhT){
  int b = blockIdx.x;
  const float* src = Wx; u16* dst = WxT;
  if (b >= 512){ src = Wh; dst = WhT; b -= 512; }
  int id = b * 256 + threadIdx.x;       // 131072 ids: 2048 cols x 64 k-chunks
  int n  = id & (FOURH - 1);            // source col (consecutive per lane -> coalesced)
  int kc = (id >> 11) << 3;             // k chunk of 8
  u32 w[4];
  #pragma unroll
  for (int j = 0; j < 4; j++){
    u32 lo = (u32)f2bf(src[(kc + 2*j    ) * FOURH + n]);
    u32 hi = (u32)f2bf(src[(kc + 2*j + 1) * FOURH + n]);
    w[j] = lo | (hi << 16);
  }
  uint4 q; q.x = w[0]; q.y = w[1]; q.z = w[2]; q.w = w[3];
  *(uint4*)(dst + n * DIM + kc) = q;
}

// ---- convert W_embed (10000 x 512 fp32) -> bf16, same layout ----
__global__ void k_wemb(const float* __restrict__ Wemb, u16* __restrict__ We16){
  int i = blockIdx.x * 256 + threadIdx.x;        // 2,560,000 ids, 2 elems each
  float2 f = *(const float2*)(Wemb + 2 * i);
  u32 pk = (u32)f2bf(f.x) | ((u32)f2bf(f.y) << 16);
  *(u32*)(We16 + 2 * i) = pk;
}

// ---- init h buffers (hi/lo split of fp32 h0) + barrier flags ----
__global__ void k_init(const float* __restrict__ h0, u16* __restrict__ h_hi,
                       u16* __restrict__ h_lo, u32* flags){
  int i = blockIdx.x * 256 + threadIdx.x;   // 32768
  float f = h0[i];
  u16 hb = f2bf(f);
  h_hi[i] = hb;
  h_lo[i] = f2bf(f - bf2f(hb));
  if (i < GBLK * FLGSTR) flags[i] = 0;
}

// ---- E = W_embed @ Wx + b  (10000 x 2048, bf16) ----
__launch_bounds__(256)
__global__ void k_egemm(const u16* __restrict__ Wemb, const u16* __restrict__ WxT,
                        const float* __restrict__ bias, u16* __restrict__ E){
  int nb = blockIdx.x;            // 0..15  -> cols nb*128
  int mb = blockIdx.y;            // 0..78  -> rows mb*128
  int wv   = threadIdx.x >> 6;
  int lane = threadIdx.x & 63;
  int l31 = lane & 31, hi5 = lane >> 5;
  int mrow = mb * 128 + wv * 32 + l31;
  int mcl  = mrow < VOCAB ? mrow : VOCAB - 1;
  const u16* ap  = Wemb + (u32)mcl * DIM + hi5 * 8;
  const u16* bp0 = WxT + (u32)(nb * 128 +  0 + l31) * DIM + hi5 * 8;
  const u16* bp1 = bp0 + 32 * DIM;
  const u16* bp2 = bp0 + 64 * DIM;
  const u16* bp3 = bp0 + 96 * DIM;
  f32x16 acc[4] = {};
  for (int ks = 0; ks < 32; ks++){
    bf16x8 av = ldfrag(ap);  ap  += 16;
    bf16x8 b0 = ldfrag(bp0); bp0 += 16;
    bf16x8 b1 = ldfrag(bp1); bp1 += 16;
    bf16x8 b2 = ldfrag(bp2); bp2 += 16;
    bf16x8 b3 = ldfrag(bp3); bp3 += 16;
    acc[0] = __builtin_amdgcn_mfma_f32_32x32x16_bf16(av, b0, acc[0], 0, 0, 0);
    acc[1] = __builtin_amdgcn_mfma_f32_32x32x16_bf16(av, b1, acc[1], 0, 0, 0);
    acc[2] = __builtin_amdgcn_mfma_f32_32x32x16_bf16(av, b2, acc[2], 0, 0, 0);
    acc[3] = __builtin_amdgcn_mfma_f32_32x32x16_bf16(av, b3, acc[3], 0, 0, 0);
  }
  int rbase = mb * 128 + wv * 32 + 4 * hi5;
  #pragma unroll
  for (int nt = 0; nt < 4; nt++){
    int col = nb * 128 + nt * 32 + l31;
    float bv = bias[col];
    #pragma unroll
    for (int r = 0; r < 16; r++){
      int row = rbase + (r & 3) + 8 * (r >> 2);
      if (row < VOCAB) E[(u32)row * FOURH + col] = f2bf(acc[nt][r] + bv);
    }
  }
}

// ---- persistent LSTM scan ----
// 64 blocks x 128 threads. Block g owns hidden dims [g*8, g*8+8).
// GEMM computed transposed: D = WhSlice^T(32 x K) . h^T(K x 32n) so that
// gate = reg&3 lands in the register dim -> all 4 gates in-lane.
//
// Coherence scheme (NO cache invalidates anywhere):
//  - h published via relaxed agent-scope atomic stores (write-through, 8B
//    granule packed 16B/lane) -> data lands at the coherence point.
//  - __syncthreads() drains vmcnt in every wave, so all h stores are globally
//    visible before tid0 issues the (relaxed) flag store.
//  - consumers poll relaxed agent flags, then read h with relaxed agent-scope
//    8B atomic loads (coherence-point reads). No acquire fence -> E, cap, Wh
//    stay L1/L2-cached across all 1024 steps.
__launch_bounds__(128, 1)
__global__ void k_scan(const int* __restrict__ cap, const u16* __restrict__ E,
                       const u16* __restrict__ WhT, u16* __restrict__ h_hi,
                       u16* __restrict__ h_lo, u32* flags, float* __restrict__ out){
  const int g    = blockIdx.x;
  const int tid  = threadIdx.x;
  const int wv   = tid >> 6;
  const int lane = tid & 63;
  const int l31  = lane & 31, hi5 = lane >> 5;
  const int n    = wv * 32 + l31;                       // batch row (B-operand col)
  // A-operand row r_loc = l31 -> global Wh column:
  const int gc   = (l31 & 3) * HID + g * 8 + (l31 >> 2);
  const u16* wbase = WhT + (u32)gc * DIM + hi5 * 8;

  // Wh slice is static across all 1024 steps: hold it in registers (128 VGPRs).
  bf16x8 wreg[32];
  #pragma unroll
  for (int ks = 0; ks < 32; ks++) wreg[ks] = ldfrag(wbase + 16 * ks);

  float c0 = 0.f, c1 = 0.f, c2 = 0.f, c3 = 0.f;

  // prefetch E row for t=0 and caption index for t=1 (2-deep cap pipeline:
  // the cap load and its dependent E load are split across step periods, so
  // the 2-level pointer chase is never serial on the step critical path).
  {
    int cv0 = cap[n * T1];
    const u16* eb = E + (u32)cv0 * FOURH + g * 8;
    (void)eb;
  }
  int cv0 = cap[n * T1];
  const u16* eb = E + (u32)cv0 * FOURH + g * 8;
  uint4 e0 = *(const uint4*)(eb + 0 * HID);
  uint4 e1 = *(const uint4*)(eb + 1 * HID);
  uint4 e2 = *(const uint4*)(eb + 2 * HID);
  uint4 e3 = *(const uint4*)(eb + 3 * HID);
  int cvn = cap[n * T1 + 1];          // caption for step t=1

  for (int t = 0; t < T_STEPS; t++){
    // acc init from prefetched E (xW + b contribution) — independent of other
    // blocks' h, done BEFORE the wait to shorten the post-barrier path.
    u32 ew[16];
    *(uint4*)&ew[0]  = e0; *(uint4*)&ew[4]  = e1;
    *(uint4*)&ew[8]  = e2; *(uint4*)&ew[12] = e3;
    f32x16 acc;
    #pragma unroll
    for (int reg = 0; reg < 16; reg++){
      int gate = reg & 3, q = reg >> 2;
      u32 d = ew[gate * 4 + q];
      acc[reg] = bf2f(hi5 ? (u16)(d >> 16) : (u16)(d & 0xFFFFu));
    }
    f32x16 acc2 = {};

    if (t > 0){
      if (tid < 64){
        u32 v;
        do {
          v = __hip_atomic_load(&flags[lane * FLGSTR], __ATOMIC_RELAXED,
                                __HIP_MEMORY_SCOPE_AGENT);
        } while (__ballot(v < (u32)t));
        // no fence: h is read via coherence-point atomic loads below
      }
      __syncthreads();
    }

    // K-loop: a += Wh^T-slice . h  (h = hi + lo bf16 pair, fp32 accumulate)
    // h fragments read with coherent 8B atomic loads (see ldfrag_coh).
    const u16* hp = h_hi + (t & 1) * (N_B * HID) + n * HID + hi5 * 8;
    const u16* lp = h_lo + (t & 1) * (N_B * HID) + n * HID + hi5 * 8;
    #pragma unroll
    for (int ks = 0; ks < 32; ks++){
      bf16x8 bhf = ldfrag_coh(hp); hp += 16;
      bf16x8 blf = ldfrag_coh(lp); lp += 16;
      acc  = __builtin_amdgcn_mfma_f32_32x32x16_bf16(wreg[ks], bhf, acc,  0, 0, 0);
      acc2 = __builtin_amdgcn_mfma_f32_32x32x16_bf16(wreg[ks], blf, acc2, 0, 0, 0);
    }
    acc += acc2;

    // LSTM cell: lane holds gates for (n, hd = g*8 + 2q + hi5), q = 0..3
    u16* hw = h_hi + ((t + 1) & 1) * (N_B * HID);
    u16* lw = h_lo + ((t + 1) & 1) * (N_B * HID);
    const int hbase = n * HID + g * 8;
    float hq0, hq1, hq2, hq3;
    u32 wh[4], wl[4];
    #pragma unroll
    for (int q = 0; q < 4; q++){
      float ai = acc[q * 4 + 0], af = acc[q * 4 + 1];
      float ao = acc[q * 4 + 2], ag = acc[q * 4 + 3];
      float ig = fsig(ai), fg = fsig(af), og = fsig(ao), gg = ftanh(ag);
      float cc = (q == 0 ? c0 : q == 1 ? c1 : q == 2 ? c2 : c3);
      cc = fg * cc + ig * gg;
      if (q == 0) c0 = cc; else if (q == 1) c1 = cc; else if (q == 2) c2 = cc; else c3 = cc;
      float h = og * ftanh(cc);
      if (q == 0) hq0 = h; else if (q == 1) hq1 = h; else if (q == 2) hq2 = h; else hq3 = h;
      // bf16 hi/lo carry for the recurrence
      u32 hb = f2bf(h);
      float rem = h - bf2f((u16)hb);
      u32 lb = f2bf(rem);
      u32 ph = (u32)__shfl_xor((int)hb, 32);
      u32 pl = (u32)__shfl_xor((int)lb, 32);
      wh[q] = hb | (ph << 16);
      wl[q] = lb | (pl << 16);
    }
    if (hi5 == 0){
      // packed 16B write-through publish (dims g*8 .. g*8+7 for row n)
      st_coh16(hw + hbase, wh[0], wh[1], wh[2], wh[3]);
      st_coh16(lw + hbase, wl[0], wl[1], wl[2], wl[3]);
    }
    __syncthreads();            // every wave drains vmcnt before s_barrier =>
                                // all h stores are at the coherence point
    if (tid == 0)
      __hip_atomic_store(&flags[g * FLGSTR], (u32)(t + 1),
                         __ATOMIC_RELAXED, __HIP_MEMORY_SCOPE_AGENT);

    // off the critical path (after publish): fp32 out stores + E prefetch for
    // t+1 (uses cvn loaded one full step ago) + cap load for t+2.
    const int obase = n * (T_STEPS * HID) + t * HID + g * 8;
    __builtin_nontemporal_store(hq0, &out[obase + 0 + hi5]);
    __builtin_nontemporal_store(hq1, &out[obase + 2 + hi5]);
    __builtin_nontemporal_store(hq2, &out[obase + 4 + hi5]);
    __builtin_nontemporal_store(hq3, &out[obase + 6 + hi5]);
    const u16* eb2 = E + (u32)cvn * FOURH + g * 8;
    e0 = *(const uint4*)(eb2 + 0 * HID);
    e1 = *(const uint4*)(eb2 + 1 * HID);
    e2 = *(const uint4*)(eb2 + 2 * HID);
    e3 = *(const uint4*)(eb2 + 3 * HID);
    int idx = t + 2; if (idx > T_STEPS) idx = T_STEPS;
    cvn = cap[n * T1 + idx];
  }
}

extern "C" void kernel_launch(void* const* d_in, const int* in_sizes, int n_in,
                              void* d_out, int out_size, void* d_ws, size_t ws_size,
                              hipStream_t stream){
  const int*   cap  = (const int*)d_in[0];
  const float* h0   = (const float*)d_in[1];
  const float* Wemb = (const float*)d_in[2];
  const float* Wx   = (const float*)d_in[3];
  const float* Wh   = (const float*)d_in[4];
  const float* bias = (const float*)d_in[5];
  float* out = (float*)d_out;

  char* ws = (char*)d_ws;
  const size_t OFF_E    = 0;
  const size_t OFF_WXT  = OFF_E    + (size_t)VOCAB * FOURH * 2;   // 40,960,000
  const size_t OFF_WHT  = OFF_WXT  + (size_t)FOURH * DIM * 2;     // +2 MiB
  const size_t OFF_WE16 = OFF_WHT  + (size_t)FOURH * DIM * 2;     // +2 MiB
  const size_t OFF_HHI  = OFF_WE16 + (size_t)VOCAB * DIM * 2;     // +10.24 MB
  const size_t OFF_HLO  = OFF_HHI  + (size_t)2 * N_B * HID * 2;   // +128 KiB
  const size_t OFF_FLG  = OFF_HLO  + (size_t)2 * N_B * HID * 2;   // +128 KiB

  u16* E    = (u16*)(ws + OFF_E);
  u16* WxT  = (u16*)(ws + OFF_WXT);
  u16* WhT  = (u16*)(ws + OFF_WHT);
  u16* We16 = (u16*)(ws + OFF_WE16);
  u16* h_hi = (u16*)(ws + OFF_HHI);
  u16* h_lo = (u16*)(ws + OFF_HLO);
  u32* flg  = (u32*)(ws + OFF_FLG);

  hipLaunchKernelGGL(k_transpose, dim3(1024),   dim3(256), 0, stream, Wx, Wh, WxT, WhT);
  hipLaunchKernelGGL(k_wemb,      dim3(10000),  dim3(256), 0, stream, Wemb, We16);
  hipLaunchKernelGGL(k_init,      dim3(128),    dim3(256), 0, stream, h0, h_hi, h_lo, flg);
  hipLaunchKernelGGL(k_egemm,     dim3(16, 79), dim3(256), 0, stream, We16, WxT, bias, E);
  hipLaunchKernelGGL(k_scan,      dim3(GBLK),   dim3(128), 0, stream, cap, E, WhT, h_hi, h_lo, flg, out);
}